// Round 1
// 172.583 us; speedup vs baseline: 1.0803x; 1.0803x over previous
//
#include <hip/hip_runtime.h>
#include <hip/hip_bf16.h>

// B=1, N=128, C=128, H=8, D=16. SCALE=0.25. All I/O fp32.
// GEMMs: bf16 MFMA, split-bf16 hi/lo 3-term for fp32 quality.
// Attention planes are HI-ONLY bf16. Plane arrays: [plane][dhalf][p][8] ushort.
// v7: 8 kernels -> 5. prep = ln + 3 weight packs. tables folded into
// gemm_qkv eg-epilogue, emitted as bf16 (halves attn table reads).
// eg_i/eg_o global roundtrip removed.

#define NPOS 16384
#define CDIM 128

typedef __attribute__((ext_vector_type(8))) short bf16x8;
typedef __attribute__((ext_vector_type(8))) unsigned short u16x8;
typedef __attribute__((ext_vector_type(4))) float f32x4;

#define MFMA16(a, b, c) __builtin_amdgcn_mfma_f32_16x16x32_bf16((a), (b), (c), 0, 0, 0)

#define GLL16(gp, lp) __builtin_amdgcn_global_load_lds( \
    (const __attribute__((address_space(1))) void*)(gp), \
    (__attribute__((address_space(3))) void*)(lp), 16, 0, 0)

static __device__ __forceinline__ unsigned short f2bf(float x) {
    union { float f; unsigned int u; } v; v.f = x;
    unsigned int u = v.u;
    unsigned int r = u + 0x7FFFu + ((u >> 16) & 1u);   // RNE
    return (unsigned short)(r >> 16);
}
static __device__ __forceinline__ float bf2f(unsigned short h) {
    union { float f; unsigned int u; } v; v.u = ((unsigned int)h) << 16; return v.f;
}

// ---------------- prep: LayerNorm + all 3 weight packs, one kernel ---------
// blocks 0..4095: ln (4 rows each); 4096..4319: pack B1t; 4320..4543: pack
// B2t; 4544..4671: pack B3t (w_o, k' = (br*8+h)*16+d ordering).
__global__ __launch_bounds__(256) void prep_kernel(
    const float* __restrict__ e, const float* __restrict__ lnw,
    const float* __restrict__ lnb, unsigned short* __restrict__ e_hl,
    const float* __restrict__ wq1, const float* __restrict__ we1,
    unsigned short* __restrict__ B1t,
    const float* __restrict__ wq2, const float* __restrict__ we2,
    unsigned short* __restrict__ B2t,
    const float* __restrict__ wo, unsigned short* __restrict__ B3t)
{
    const int t = threadIdx.x;
    const int bx = blockIdx.x;
    if (bx < 4096) {
        const int lane = t & 63;
        const int row = bx * 4 + (t >> 6);
        float2 x = *(const float2*)(e + (size_t)row * CDIM + lane * 2);
        float s = x.x + x.y, s2 = x.x * x.x + x.y * x.y;
        #pragma unroll
        for (int off = 1; off < 64; off <<= 1) {
            s  += __shfl_xor(s,  off, 64);
            s2 += __shfl_xor(s2, off, 64);
        }
        float m = s * (1.f / 128.f);
        float v = s2 * (1.f / 128.f) - m * m;
        float sc = rsqrtf(v + 1e-5f);
        float2 wv = *(const float2*)(lnw + lane * 2);
        float2 bv = *(const float2*)(lnb + lane * 2);
        float y0 = (x.x - m) * sc * wv.x + bv.x;
        float y1 = (x.y - m) * sc * wv.y + bv.y;
        unsigned short h0 = f2bf(y0), h1 = f2bf(y1);
        ushort2 hi = {h0, h1};
        ushort2 lo = {f2bf(y0 - bf2f(h0)), f2bf(y1 - bf2f(h1))};
        *(ushort2*)(e_hl + (size_t)row * 256 + lane * 2)       = hi;
        *(ushort2*)(e_hl + (size_t)row * 256 + 128 + lane * 2) = lo;
    } else if (bx < 4544) {
        int pb = bx - 4096;
        const float* wq; const float* we; unsigned short* Bt;
        if (pb < 224) { wq = wq1; we = we1; Bt = B1t; }
        else          { pb -= 224; wq = wq2; we = we2; Bt = B2t; }
        const int idx = pb * 256 + t;    // n*128 + k
        const int n = idx >> 7, k = idx & 127;
        float v = 0.f;
        if (n < 384) v = wq[(size_t)k * 384 + n];
        else if (n < 400) v = we[(size_t)k * 16 + (n - 384)];
        unsigned short hi = f2bf(v);
        Bt[idx] = hi;
        Bt[448 * 128 + idx] = f2bf(v - bf2f(hi));
    } else {
        const int idx = (bx - 4544) * 256 + t;   // n*256 + kp
        const int n = idx >> 8, kp = idx & 255;
        const int d = kp & 15, pl = kp >> 4;
        const int k = d * 16 + pl;
        float v = wo[(size_t)k * 128 + n];
        unsigned short hi = f2bf(v);
        B3t[idx] = hi;
        B3t[128 * 256 + idx] = f2bf(v - bf2f(hi));
    }
}

// ---------------- MFMA GEMM v3: qkv+eg, global_load_lds staging ----------
// grid(128, 7, 2), 256 thr. Tile 128(M) x 64(N). K=128 in 4 chunks.
// LDS: A [hl][q][128 row][16B] 16KB, B [hl][q][64 col][16B] 8KB (aliased by
// the epilogue Ts tile). by 0,1: Q d-halves; 2,3: K; 4,5: V; 6: eg -> tables.
// by==6 epilogue directly emits bf16 Etab/Gtab (tables kernel folded in).
__global__ __launch_bounds__(256) void gemm_qkv_kernel(
    const unsigned short* __restrict__ e_hl,
    const unsigned short* __restrict__ B1t, const unsigned short* __restrict__ B2t,
    const float* __restrict__ bq_i, const float* __restrict__ be_i,
    const float* __restrict__ bq_o, const float* __restrict__ be_o,
    const float* __restrict__ mask,
    unsigned short* __restrict__ QT, unsigned short* __restrict__ KT,
    unsigned short* __restrict__ VT,
    unsigned short* __restrict__ Etab, unsigned short* __restrict__ Gtab)
{
    __shared__ __align__(16) unsigned char smem[24576];
    unsigned short* Alds = (unsigned short*)smem;            // [2][4][128][8] ushorts
    unsigned short* Blds = (unsigned short*)(smem + 16384);  // [2][4][64][8]

    const int t = threadIdx.x;
    const int wave = t >> 6, lane = t & 63;
    const int m = lane & 15, q = lane >> 4;
    const int bx = blockIdx.x;
    const int W0blk = bx * 128;
    const int by = blockIdx.y;
    const int N0 = by * 64;
    const int br = blockIdx.z;
    const unsigned short* Bt = br ? B2t : B1t;
    const float* bias_qkv = br ? bq_o : bq_i;
    const float* bias_eg  = br ? be_o : be_i;

    f32x4 acc[2][4];
    #pragma unroll
    for (int a = 0; a < 2; ++a)
        #pragma unroll
        for (int c = 0; c < 4; ++c) acc[a][c] = (f32x4){0.f, 0.f, 0.f, 0.f};

    for (int kc = 0; kc < 4; ++kc) {
        // ---- stage A+B chunk into LDS: 24 wave-instrs, 6 per wave ----
        #pragma unroll
        for (int ii = 0; ii < 6; ++ii) {
            const int id = wave + ii * 4;
            if (id < 16) {
                const int hl = id >> 3, s = id & 7;
                const int qq = s >> 1, rbase = (s & 1) * 64;
                const unsigned short* g = e_hl
                    + (size_t)(W0blk + rbase + lane) * 256 + hl * 128 + kc * 32 + qq * 8;
                unsigned short* l = Alds + hl * 4096 + qq * 1024 + rbase * 8;
                GLL16(g, l);
            } else {
                const int id2 = id - 16;
                const int hl = id2 >> 2, qq = id2 & 3;
                const unsigned short* g = Bt + (size_t)(N0 + lane) * 128
                    + hl * (448 * 128) + kc * 32 + qq * 8;
                unsigned short* l = Blds + hl * 2048 + qq * 512;
                GLL16(g, l);
            }
        }
        __syncthreads();   // drains vmcnt: staged data visible

        bf16x8 aH[2], aL[2], bH[4], bL[4];
        #pragma unroll
        for (int ms = 0; ms < 2; ++ms) {
            const int row = wave * 32 + ms * 16 + m;
            aH[ms] = *(const bf16x8*)(Alds + 0    + q * 1024 + row * 8);
            aL[ms] = *(const bf16x8*)(Alds + 4096 + q * 1024 + row * 8);
        }
        #pragma unroll
        for (int ns = 0; ns < 4; ++ns) {
            bH[ns] = *(const bf16x8*)(Blds + 0    + q * 512 + (ns * 16 + m) * 8);
            bL[ns] = *(const bf16x8*)(Blds + 2048 + q * 512 + (ns * 16 + m) * 8);
        }
        #pragma unroll
        for (int ns = 0; ns < 4; ++ns) {
            acc[0][ns] = MFMA16(aH[0], bH[ns], acc[0][ns]);
            acc[1][ns] = MFMA16(aH[1], bH[ns], acc[1][ns]);
        }
        #pragma unroll
        for (int ns = 0; ns < 4; ++ns) {
            acc[0][ns] = MFMA16(aL[0], bH[ns], acc[0][ns]);
            acc[1][ns] = MFMA16(aL[1], bH[ns], acc[1][ns]);
        }
        #pragma unroll
        for (int ns = 0; ns < 4; ++ns) {
            acc[0][ns] = MFMA16(aH[0], bL[ns], acc[0][ns]);
            acc[1][ns] = MFMA16(aH[1], bL[ns], acc[1][ns]);
        }
        __syncthreads();   // LDS reusable (next chunk / epilogue)
    }

    // ---- epilogue: reuse smem as Ts16[128][66] (bf16) or Tf[128][33] (f32) ----
    if (by < 6) {
        unsigned short (*Ts16)[66] = (unsigned short (*)[66])smem;
        #pragma unroll
        for (int ms = 0; ms < 2; ++ms)
            #pragma unroll
            for (int ns = 0; ns < 4; ++ns) {
                const int lc = ns * 16 + m;
                const int col = N0 + lc;
                const float bias = bias_qkv[col];
                const float scale = (col < 128) ? 0.25f : 1.f;
                #pragma unroll
                for (int r = 0; r < 4; ++r) {
                    const int lr = wave * 32 + ms * 16 + q * 4 + r;
                    Ts16[lr][lc] = f2bf((acc[ms][ns][r] + bias) * scale);
                }
            }
        __syncthreads();
        const int qsel = by >> 1, dhalf = by & 1;
        unsigned short* dstH = (qsel == 0) ? QT : (qsel == 1 ? KT : VT);
        #pragma unroll
        for (int it = 0; it < 4; ++it) {
            int item = it * 256 + t;        // 0..1023: (hh, lr)
            int hh = item >> 7, lr = item & 127;
            u16x8 hi;
            #pragma unroll
            for (int dd = 0; dd < 8; ++dd)
                hi[dd] = Ts16[lr][dd * 8 + hh];
            size_t addr = (((size_t)(br * 8 + hh) * 2 + dhalf) * NPOS
                           + (size_t)bx * 128 + lr) * 8;   // i-major, dense
            *(u16x8*)(dstH + addr) = hi;
        }
    } else {
        float* Tf = (float*)smem;   // [128][33], cols 0..15 used
        #pragma unroll
        for (int ms = 0; ms < 2; ++ms) {
            const float bias = bias_eg[m];
            #pragma unroll
            for (int r = 0; r < 4; ++r) {
                const int lr = wave * 32 + ms * 16 + q * 4 + r;
                Tf[lr * 33 + m] = acc[ms][0][r] + bias;
            }
        }
        __syncthreads();
        // table emission (was tables_kernel). Row p = bx*128 + r128.
        // br=0: dst = p; br=1: dst = (p&127)*128 + (p>>7) = r128*128 + bx.
        const int r128 = t & 127, grp = t >> 7;
        const float mk = mask[bx * 128 + r128];
        const int dst = br ? (r128 * 128 + bx) : (bx * 128 + r128);
        if (grp == 0) {
            #pragma unroll
            for (int h = 0; h < 8; ++h)
                Etab[(size_t)(br * 8 + h) * NPOS + dst] =
                    f2bf(Tf[r128 * 33 + h] + mk);
        } else {
            #pragma unroll
            for (int h = 0; h < 8; ++h) {
                const float g = Tf[r128 * 33 + 8 + h] + mk;
                Gtab[(size_t)(br * 8 + h) * NPOS + dst] =
                    f2bf(1.f / (1.f + __expf(-g)));
            }
        }
    }
}

// ---------------- In-place sub-plane transpose (i-major -> j-major) ----------
// Sub-plane = [128][128] matrix of 16B elements. grid(36, 64): x = tile pair
// (a<=b) of 16x16-element tiles, y = sub-plane selector:
//   0..31 QT (all), 32..47 KT (br=1), 48..63 VT (br=1).
__global__ __launch_bounds__(256) void transpose_kernel(
    unsigned short* __restrict__ QT, unsigned short* __restrict__ KT,
    unsigned short* __restrict__ VT)
{
    const int s = blockIdx.y;
    unsigned short* base;
    int sub;
    if (s < 32)       { base = QT; sub = s; }
    else if (s < 48)  { base = KT; sub = 16 + (s - 32); }
    else              { base = VT; sub = 16 + (s - 48); }
    unsigned short* P = base + (size_t)sub * NPOS * 8;

    int x = blockIdx.x, a = 0;
    while (x >= 8 - a) { x -= 8 - a; ++a; }
    const int b = a + x;

    __shared__ unsigned short T1[16][136];   // pad 8 -> 2-way max
    __shared__ unsigned short T2[16][136];

    const int t = threadIdx.x;
    const int r = t >> 4, c = t & 15;

    u16x8 v1 = *(const u16x8*)(P + ((size_t)(a * 16 + r) * 128 + b * 16 + c) * 8);
    *(u16x8*)&T1[r][c * 8] = v1;
    if (a != b) {
        u16x8 v2 = *(const u16x8*)(P + ((size_t)(b * 16 + r) * 128 + a * 16 + c) * 8);
        *(u16x8*)&T2[r][c * 8] = v2;
    }
    __syncthreads();

    u16x8 w1 = *(const u16x8*)&T1[c][r * 8];
    *(u16x8*)(P + ((size_t)(b * 16 + r) * 128 + a * 16 + c) * 8) = w1;
    if (a != b) {
        u16x8 w2 = *(const u16x8*)&T2[c][r * 8];
        *(u16x8*)(P + ((size_t)(a * 16 + r) * 128 + b * 16 + c) * 8) = w2;
    }
}

// ---------------- MFMA GEMM: output projection (va in p'/k' order) ----------------
// grid(256, 2), 256 thr. Tile 64(M) x 64(N). K=256. Row-permuted C store.
__global__ __launch_bounds__(256) void gemm_out_kernel(
    const float* __restrict__ va,
    const unsigned short* __restrict__ B3t,
    const float* __restrict__ bias,
    float* __restrict__ out)
{
    const int t = threadIdx.x;
    const int wave = t >> 6, lane = t & 63;
    const int m = lane & 15, q = lane >> 4;
    const int W0 = blockIdx.x * 64 + wave * 16;
    const int N0 = blockIdx.y * 64;

    f32x4 acc[4];
    #pragma unroll
    for (int c = 0; c < 4; ++c) acc[c] = (f32x4){0.f, 0.f, 0.f, 0.f};

    const float* arow = va + (size_t)(W0 + m) * 256;
    const unsigned short* bcol[4];
    #pragma unroll
    for (int ns = 0; ns < 4; ++ns)
        bcol[ns] = B3t + (size_t)(N0 + ns * 16 + m) * 256;

    #pragma unroll 2
    for (int kc = 0; kc < 8; ++kc) {
        const int ko = kc * 32 + q * 8;
        const float4* ap = (const float4*)(arow + ko);
        float4 f0 = ap[0], f1 = ap[1];
        float xs[8] = {f0.x, f0.y, f0.z, f0.w, f1.x, f1.y, f1.z, f1.w};
        bf16x8 ah, al;
        #pragma unroll
        for (int jj = 0; jj < 8; ++jj) {
            unsigned short h = f2bf(xs[jj]);
            ah[jj] = (short)h;
            al[jj] = (short)f2bf(xs[jj] - bf2f(h));
        }
        bf16x8 bh[4], bl[4];
        #pragma unroll
        for (int ns = 0; ns < 4; ++ns) {
            bh[ns] = *(const bf16x8*)(bcol[ns] + ko);
            bl[ns] = *(const bf16x8*)(bcol[ns] + 128 * 256 + ko);
        }
        #pragma unroll
        for (int ns = 0; ns < 4; ++ns) acc[ns] = MFMA16(ah, bh[ns], acc[ns]);
        #pragma unroll
        for (int ns = 0; ns < 4; ++ns) acc[ns] = MFMA16(al, bh[ns], acc[ns]);
        #pragma unroll
        for (int ns = 0; ns < 4; ++ns) acc[ns] = MFMA16(ah, bl[ns], acc[ns]);
    }

    #pragma unroll
    for (int ns = 0; ns < 4; ++ns) {
        const int col = N0 + ns * 16 + m;
        #pragma unroll
        for (int r = 0; r < 4; ++r) {
            const int prow = W0 + q * 4 + r;                 // p' = j*128+i
            const int orow = ((prow & 127) << 7) | (prow >> 7);  // i*128+j
            out[(size_t)orow * 128 + col] = acc[ns][r] + bias[col];
        }
    }
}

// ---------------- MFMA fused triangle attention v7 (bf16 E/G tables) --------
// grid (j=128, h=8, br=2), 256 thr = 4 waves, wave owns 32-row strip.
// S-column c maps to K-row k(c) = (c&15)*8 + (c>>4); softmax is k-permutation
// invariant, and P/V use the same order, so the result is exact.
__global__ __launch_bounds__(256) void attn_kernel(
    const unsigned short* __restrict__ QT, const unsigned short* __restrict__ KT,
    const unsigned short* __restrict__ VT,
    const unsigned short* __restrict__ Etab, const unsigned short* __restrict__ Gtab,
    float* __restrict__ va)
{
    const int j = blockIdx.x, h = blockIdx.y, br = blockIdx.z;
    const int t = threadIdx.x;
    const int wave = t >> 6, lane = t & 63;
    const int m = lane & 15, q = lane >> 4;
    const int plane = br * 8 + h;
    const size_t SP = (size_t)NPOS * 8;          // ushorts per sub-plane
    const size_t jb = (size_t)j * 128 * 8;
    const unsigned short* __restrict__ Eb = Etab + (size_t)plane * NPOS;
    const unsigned short* __restrict__ Gb = Gtab + (size_t)plane * NPOS;

    __shared__ unsigned short Vth[16 * 136];
    __shared__ unsigned short Pl[128 * 136];

    const int strip = wave * 32;

    // ---- E preload into the MFMA accumulator (one u16x8 per (mt,r)) ----
    f32x4 S[2][8];
    #pragma unroll
    for (int mt = 0; mt < 2; ++mt)
        #pragma unroll
        for (int r = 0; r < 4; ++r) {
            const int i = strip + mt * 16 + q * 4 + r;
            u16x8 ev = *(const u16x8*)(Eb + (size_t)i * 128 + m * 8);
            #pragma unroll
            for (int nt = 0; nt < 8; ++nt) S[mt][nt][r] = bf2f(ev[nt]);
        }

    // stage V transposed+permuted into LDS: Vth[d*136 + c] = V[k(c)][d]
    {
        int c = t >> 1, ch = t & 1;
        int krow = (c & 15) * 8 + (c >> 4);
        const unsigned short* src = VT + (size_t)(plane * 2 + ch) * SP + jb
                                  + (size_t)krow * 8;
        u16x8 v = *(const u16x8*)src;
        #pragma unroll
        for (int dd = 0; dd < 8; ++dd)
            Vth[(ch * 8 + dd) * 136 + c] = v[dd];
    }

    const bf16x8 zero8 = {};
    const int hf = q & 1;
    const size_t qko = (size_t)(plane * 2 + hf) * SP + jb;

    // Q A-frags (direct from global; q>=2 lanes = zero K-half)
    bf16x8 aQ[2];
    #pragma unroll
    for (int mt = 0; mt < 2; ++mt) {
        const size_t off = qko + (size_t)(strip + mt * 16 + m) * 8;
        aQ[mt] = (q < 2) ? *(const bf16x8*)(QT + off) : zero8;
    }

    // S tiles: B row for tile nt, lane m = K row k = m*8 + nt (permuted)
    #pragma unroll
    for (int nt = 0; nt < 8; ++nt) {
        const size_t koff = qko + (size_t)(m * 8 + nt) * 8;
        bf16x8 bK = (q < 2) ? *(const bf16x8*)(KT + koff) : zero8;
        #pragma unroll
        for (int mt = 0; mt < 2; ++mt)
            S[mt][nt] = MFMA16(aQ[mt], bK, S[mt][nt]);
    }

    // softmax (row cols spread over lanes m: xor 1,2,4,8) + gate + P -> LDS
    #pragma unroll
    for (int mt = 0; mt < 2; ++mt)
        #pragma unroll
        for (int r = 0; r < 4; ++r) {
            float v = -1e30f;
            #pragma unroll
            for (int nt = 0; nt < 8; ++nt) v = fmaxf(v, S[mt][nt][r]);
            v = fmaxf(v, __shfl_xor(v, 1)); v = fmaxf(v, __shfl_xor(v, 2));
            v = fmaxf(v, __shfl_xor(v, 4)); v = fmaxf(v, __shfl_xor(v, 8));
            float s = 0.f;
            #pragma unroll
            for (int nt = 0; nt < 8; ++nt) {
                float p = __expf(S[mt][nt][r] - v);
                S[mt][nt][r] = p;
                s += p;
            }
            s += __shfl_xor(s, 1); s += __shfl_xor(s, 2);
            s += __shfl_xor(s, 4); s += __shfl_xor(s, 8);
            const float inv = 1.f / s;
            const int i = strip + mt * 16 + q * 4 + r;
            u16x8 gv = *(const u16x8*)(Gb + (size_t)i * 128 + m * 8);
            #pragma unroll
            for (int nt = 0; nt < 4; ++nt) {
                Pl[i * 136 + nt * 16 + m] =
                    f2bf(S[mt][nt][r] * inv * bf2f(gv[nt]));
                Pl[i * 136 + (nt + 4) * 16 + m] =
                    f2bf(S[mt][nt + 4][r] * inv * bf2f(gv[nt + 4]));
            }
        }

    __syncthreads();   // Vt ready (and P via lgkm drain)

    // AV = P @ V (both in permuted-k order)
    f32x4 av[2] = {(f32x4){0.f, 0.f, 0.f, 0.f}, (f32x4){0.f, 0.f, 0.f, 0.f}};
    #pragma unroll
    for (int kc = 0; kc < 4; ++kc) {
        const int off = kc * 32 + q * 8;
        bf16x8 bV = *(const bf16x8*)&Vth[m * 136 + off];
        #pragma unroll
        for (int mt = 0; mt < 2; ++mt) {
            bf16x8 aP = *(const bf16x8*)&Pl[(strip + mt * 16 + m) * 136 + off];
            av[mt] = MFMA16(aP, bV, av[mt]);
        }
    }

    // store va' (row p' = j*128+i, col k' = plane*16 + d): 64B-line coalesced
    #pragma unroll
    for (int mt = 0; mt < 2; ++mt)
        #pragma unroll
        for (int r = 0; r < 4; ++r) {
            const int i = strip + mt * 16 + q * 4 + r;
            va[((size_t)(j * 128 + i)) * 256 + plane * 16 + m] = av[mt][r];
        }
}

extern "C" void kernel_launch(void* const* d_in, const int* in_sizes, int n_in,
                              void* d_out, int out_size, void* d_ws, size_t ws_size,
                              hipStream_t stream) {
    const float* e        = (const float*)d_in[0];
    const float* mask     = (const float*)d_in[1];
    const float* ln_w     = (const float*)d_in[2];
    const float* ln_b     = (const float*)d_in[3];
    const float* w_qkv_in = (const float*)d_in[4];
    const float* b_qkv_in = (const float*)d_in[5];
    const float* w_eg_in  = (const float*)d_in[6];
    const float* b_eg_in  = (const float*)d_in[7];
    const float* w_qkv_o  = (const float*)d_in[8];
    const float* b_qkv_o  = (const float*)d_in[9];
    const float* w_eg_o   = (const float*)d_in[10];
    const float* b_eg_o   = (const float*)d_in[11];
    const float* w_o      = (const float*)d_in[12];
    const float* b_o      = (const float*)d_in[13];
    float* out = (float*)d_out;

    char* base = (char*)d_ws;
    const size_t PLANE = (size_t)16 * NPOS * 16;                      // ushorts per array
    unsigned short* e_hl = (unsigned short*)base;                     // 8.39 MB
    unsigned short* QT = (unsigned short*)(base + (size_t)NPOS * 256 * 2);
    unsigned short* KT = QT + PLANE;
    unsigned short* VT = KT + PLANE;
    float* va = (float*)(VT + PLANE);                                 // 16.78 MB
    unsigned short* Etab = (unsigned short*)(va + (size_t)NPOS * 256);// 0.52 MB (bf16)
    unsigned short* Gtab = Etab + (size_t)16 * NPOS;                  // 0.52 MB
    unsigned short* B3t  = Gtab + (size_t)16 * NPOS;                  // 0.13 MB

    // aliases (lifetime-checked): B1t/B2t overlay va (dead before attn writes)
    unsigned short* B1t = (unsigned short*)va;
    unsigned short* B2t = B1t + (size_t)2 * 448 * 128;

    prep_kernel<<<4672, 256, 0, stream>>>(
        e, ln_w, ln_b, e_hl,
        w_qkv_in, w_eg_in, B1t, w_qkv_o, w_eg_o, B2t, w_o, B3t);

    gemm_qkv_kernel<<<dim3(128, 7, 2), 256, 0, stream>>>(
        e_hl, B1t, B2t, b_qkv_in, b_eg_in, b_qkv_o, b_eg_o, mask,
        QT, KT, VT, Etab, Gtab);

    transpose_kernel<<<dim3(36, 64), 256, 0, stream>>>(QT, KT, VT);

    attn_kernel<<<dim3(128, 8, 2), 256, 0, stream>>>(
        QT, KT, VT, Etab, Gtab, va);

    gemm_out_kernel<<<dim3(256, 2), 256, 0, stream>>>(va, B3t, b_o, out);
}

// Round 2
// 167.705 us; speedup vs baseline: 1.1117x; 1.0291x over previous
//
#include <hip/hip_runtime.h>
#include <hip/hip_bf16.h>

// B=1, N=128, C=128, H=8, D=16. SCALE=0.25. All I/O fp32.
// GEMMs: bf16 MFMA, split-bf16 hi/lo 3-term for fp32 quality.
// Attention planes are HI-ONLY bf16. Plane arrays: [plane][dhalf][p][8] ushort.
// v8: 5 kernels -> 4. transpose_kernel folded into gemm_qkv epilogue:
// subplanes that attn reads column-wise (Q all, K/V br=1) are stored j-major
// directly (scattered 16B stores; bx-quad XCD swizzle so L2 assembles lines).
// gemm_out: 64x128 tile, grid(256,1) -> va read once, 1 block/CU.

#define NPOS 16384
#define CDIM 128

typedef __attribute__((ext_vector_type(8))) short bf16x8;
typedef __attribute__((ext_vector_type(8))) unsigned short u16x8;
typedef __attribute__((ext_vector_type(4))) float f32x4;

#define MFMA16(a, b, c) __builtin_amdgcn_mfma_f32_16x16x32_bf16((a), (b), (c), 0, 0, 0)

#define GLL16(gp, lp) __builtin_amdgcn_global_load_lds( \
    (const __attribute__((address_space(1))) void*)(gp), \
    (__attribute__((address_space(3))) void*)(lp), 16, 0, 0)

static __device__ __forceinline__ unsigned short f2bf(float x) {
    union { float f; unsigned int u; } v; v.f = x;
    unsigned int u = v.u;
    unsigned int r = u + 0x7FFFu + ((u >> 16) & 1u);   // RNE
    return (unsigned short)(r >> 16);
}
static __device__ __forceinline__ float bf2f(unsigned short h) {
    union { float f; unsigned int u; } v; v.u = ((unsigned int)h) << 16; return v.f;
}

// ---------------- prep: LayerNorm + all 3 weight packs, one kernel ---------
// blocks 0..4095: ln (4 rows each); 4096..4319: pack B1t; 4320..4543: pack
// B2t; 4544..4671: pack B3t (w_o, k' = (br*8+h)*16+d ordering).
__global__ __launch_bounds__(256) void prep_kernel(
    const float* __restrict__ e, const float* __restrict__ lnw,
    const float* __restrict__ lnb, unsigned short* __restrict__ e_hl,
    const float* __restrict__ wq1, const float* __restrict__ we1,
    unsigned short* __restrict__ B1t,
    const float* __restrict__ wq2, const float* __restrict__ we2,
    unsigned short* __restrict__ B2t,
    const float* __restrict__ wo, unsigned short* __restrict__ B3t)
{
    const int t = threadIdx.x;
    const int bx = blockIdx.x;
    if (bx < 4096) {
        const int lane = t & 63;
        const int row = bx * 4 + (t >> 6);
        float2 x = *(const float2*)(e + (size_t)row * CDIM + lane * 2);
        float s = x.x + x.y, s2 = x.x * x.x + x.y * x.y;
        #pragma unroll
        for (int off = 1; off < 64; off <<= 1) {
            s  += __shfl_xor(s,  off, 64);
            s2 += __shfl_xor(s2, off, 64);
        }
        float m = s * (1.f / 128.f);
        float v = s2 * (1.f / 128.f) - m * m;
        float sc = rsqrtf(v + 1e-5f);
        float2 wv = *(const float2*)(lnw + lane * 2);
        float2 bv = *(const float2*)(lnb + lane * 2);
        float y0 = (x.x - m) * sc * wv.x + bv.x;
        float y1 = (x.y - m) * sc * wv.y + bv.y;
        unsigned short h0 = f2bf(y0), h1 = f2bf(y1);
        ushort2 hi = {h0, h1};
        ushort2 lo = {f2bf(y0 - bf2f(h0)), f2bf(y1 - bf2f(h1))};
        *(ushort2*)(e_hl + (size_t)row * 256 + lane * 2)       = hi;
        *(ushort2*)(e_hl + (size_t)row * 256 + 128 + lane * 2) = lo;
    } else if (bx < 4544) {
        int pb = bx - 4096;
        const float* wq; const float* we; unsigned short* Bt;
        if (pb < 224) { wq = wq1; we = we1; Bt = B1t; }
        else          { pb -= 224; wq = wq2; we = we2; Bt = B2t; }
        const int idx = pb * 256 + t;    // n*128 + k
        const int n = idx >> 7, k = idx & 127;
        float v = 0.f;
        if (n < 384) v = wq[(size_t)k * 384 + n];
        else if (n < 400) v = we[(size_t)k * 16 + (n - 384)];
        unsigned short hi = f2bf(v);
        Bt[idx] = hi;
        Bt[448 * 128 + idx] = f2bf(v - bf2f(hi));
    } else {
        const int idx = (bx - 4544) * 256 + t;   // n*256 + kp
        const int n = idx >> 8, kp = idx & 255;
        const int d = kp & 15, pl = kp >> 4;
        const int k = d * 16 + pl;
        float v = wo[(size_t)k * 128 + n];
        unsigned short hi = f2bf(v);
        B3t[idx] = hi;
        B3t[128 * 256 + idx] = f2bf(v - bf2f(hi));
    }
}

// ---------------- MFMA GEMM: qkv+eg, global_load_lds staging, fused store --
// grid(128, 7, 2), 256 thr. Tile 128(M) x 64(N). K=128 in 4 chunks.
// LDS: A [hl][q][128 row][16B] 16KB, B [hl][q][64 col][16B] 8KB (aliased by
// the epilogue Ts tile). by 0,1: Q d-halves; 2,3: K; 4,5: V; 6: eg -> tables.
// Subplanes consumed column-wise by attn (Q all br, K/V br=1) are stored
// j-major directly (the old transpose kernel, folded in). bx is XCD-chunk
// swizzled so the 4 blocks sharing a 64B output line sit on one XCD's L2.
__global__ __launch_bounds__(256) void gemm_qkv_kernel(
    const unsigned short* __restrict__ e_hl,
    const unsigned short* __restrict__ B1t, const unsigned short* __restrict__ B2t,
    const float* __restrict__ bq_i, const float* __restrict__ be_i,
    const float* __restrict__ bq_o, const float* __restrict__ be_o,
    const float* __restrict__ mask,
    unsigned short* __restrict__ QT, unsigned short* __restrict__ KT,
    unsigned short* __restrict__ VT,
    unsigned short* __restrict__ Etab, unsigned short* __restrict__ Gtab)
{
    __shared__ __align__(16) unsigned char smem[24576];
    unsigned short* Alds = (unsigned short*)smem;            // [2][4][128][8] ushorts
    unsigned short* Blds = (unsigned short*)(smem + 16384);  // [2][4][64][8]

    const int t = threadIdx.x;
    const int wave = t >> 6, lane = t & 63;
    const int m = lane & 15, q = lane >> 4;
    const int c = blockIdx.x;
    const int bx = ((c & 31) << 2) | (c >> 5);   // bx quads share an XCD
    const int W0blk = bx * 128;
    const int by = blockIdx.y;
    const int N0 = by * 64;
    const int br = blockIdx.z;
    const unsigned short* Bt = br ? B2t : B1t;
    const float* bias_qkv = br ? bq_o : bq_i;
    const float* bias_eg  = br ? be_o : be_i;

    f32x4 acc[2][4];
    #pragma unroll
    for (int a = 0; a < 2; ++a)
        #pragma unroll
        for (int cc = 0; cc < 4; ++cc) acc[a][cc] = (f32x4){0.f, 0.f, 0.f, 0.f};

    for (int kc = 0; kc < 4; ++kc) {
        // ---- stage A+B chunk into LDS: 24 wave-instrs, 6 per wave ----
        #pragma unroll
        for (int ii = 0; ii < 6; ++ii) {
            const int id = wave + ii * 4;
            if (id < 16) {
                const int hl = id >> 3, s = id & 7;
                const int qq = s >> 1, rbase = (s & 1) * 64;
                const unsigned short* g = e_hl
                    + (size_t)(W0blk + rbase + lane) * 256 + hl * 128 + kc * 32 + qq * 8;
                unsigned short* l = Alds + hl * 4096 + qq * 1024 + rbase * 8;
                GLL16(g, l);
            } else {
                const int id2 = id - 16;
                const int hl = id2 >> 2, qq = id2 & 3;
                const unsigned short* g = Bt + (size_t)(N0 + lane) * 128
                    + hl * (448 * 128) + kc * 32 + qq * 8;
                unsigned short* l = Blds + hl * 2048 + qq * 512;
                GLL16(g, l);
            }
        }
        __syncthreads();   // drains vmcnt: staged data visible

        bf16x8 aH[2], aL[2], bH[4], bL[4];
        #pragma unroll
        for (int ms = 0; ms < 2; ++ms) {
            const int row = wave * 32 + ms * 16 + m;
            aH[ms] = *(const bf16x8*)(Alds + 0    + q * 1024 + row * 8);
            aL[ms] = *(const bf16x8*)(Alds + 4096 + q * 1024 + row * 8);
        }
        #pragma unroll
        for (int ns = 0; ns < 4; ++ns) {
            bH[ns] = *(const bf16x8*)(Blds + 0    + q * 512 + (ns * 16 + m) * 8);
            bL[ns] = *(const bf16x8*)(Blds + 2048 + q * 512 + (ns * 16 + m) * 8);
        }
        #pragma unroll
        for (int ns = 0; ns < 4; ++ns) {
            acc[0][ns] = MFMA16(aH[0], bH[ns], acc[0][ns]);
            acc[1][ns] = MFMA16(aH[1], bH[ns], acc[1][ns]);
        }
        #pragma unroll
        for (int ns = 0; ns < 4; ++ns) {
            acc[0][ns] = MFMA16(aL[0], bH[ns], acc[0][ns]);
            acc[1][ns] = MFMA16(aL[1], bH[ns], acc[1][ns]);
        }
        #pragma unroll
        for (int ns = 0; ns < 4; ++ns) {
            acc[0][ns] = MFMA16(aH[0], bL[ns], acc[0][ns]);
            acc[1][ns] = MFMA16(aH[1], bL[ns], acc[1][ns]);
        }
        __syncthreads();   // LDS reusable (next chunk / epilogue)
    }

    // ---- epilogue: reuse smem as Ts16[128][66] (bf16) or Tf[128][33] (f32) ----
    if (by < 6) {
        unsigned short (*Ts16)[66] = (unsigned short (*)[66])smem;
        #pragma unroll
        for (int ms = 0; ms < 2; ++ms)
            #pragma unroll
            for (int ns = 0; ns < 4; ++ns) {
                const int lc = ns * 16 + m;
                const int col = N0 + lc;
                const float bias = bias_qkv[col];
                const float scale = (col < 128) ? 0.25f : 1.f;
                #pragma unroll
                for (int r = 0; r < 4; ++r) {
                    const int lr = wave * 32 + ms * 16 + q * 4 + r;
                    Ts16[lr][lc] = f2bf((acc[ms][ns][r] + bias) * scale);
                }
            }
        __syncthreads();
        const int qsel = by >> 1, dhalf = by & 1;
        unsigned short* dstH = (qsel == 0) ? QT : (qsel == 1 ? KT : VT);
        // j-major (transposed) for the subplanes attn reads column-wise:
        const bool tr = (qsel == 0) || (br == 1);
        #pragma unroll
        for (int it = 0; it < 4; ++it) {
            int item = it * 256 + t;        // 0..1023: (hh, lr)
            int hh = item >> 7, lr = item & 127;
            u16x8 hi;
            #pragma unroll
            for (int dd = 0; dd < 8; ++dd)
                hi[dd] = Ts16[lr][dd * 8 + hh];
            const size_t sub = ((size_t)(br * 8 + hh) * 2 + dhalf) * NPOS;
            const size_t p16 = tr ? ((size_t)lr * 128 + bx)
                                  : ((size_t)bx * 128 + lr);
            *(u16x8*)(dstH + (sub + p16) * 8) = hi;
        }
    } else {
        float* Tf = (float*)smem;   // [128][33], cols 0..15 used
        #pragma unroll
        for (int ms = 0; ms < 2; ++ms) {
            const float bias = bias_eg[m];
            #pragma unroll
            for (int r = 0; r < 4; ++r) {
                const int lr = wave * 32 + ms * 16 + q * 4 + r;
                Tf[lr * 33 + m] = acc[ms][0][r] + bias;
            }
        }
        __syncthreads();
        // table emission. Row p = bx*128 + r128.
        // br=0: dst = p; br=1: dst = (p&127)*128 + (p>>7) = r128*128 + bx.
        const int r128 = t & 127, grp = t >> 7;
        const float mk = mask[bx * 128 + r128];
        const int dst = br ? (r128 * 128 + bx) : (bx * 128 + r128);
        if (grp == 0) {
            #pragma unroll
            for (int h = 0; h < 8; ++h)
                Etab[(size_t)(br * 8 + h) * NPOS + dst] =
                    f2bf(Tf[r128 * 33 + h] + mk);
        } else {
            #pragma unroll
            for (int h = 0; h < 8; ++h) {
                const float g = Tf[r128 * 33 + 8 + h] + mk;
                Gtab[(size_t)(br * 8 + h) * NPOS + dst] =
                    f2bf(1.f / (1.f + __expf(-g)));
            }
        }
    }
}

// ---------------- MFMA GEMM: output projection (va in p'/k' order) ----------
// grid(256), 256 thr. Tile 64(M) x 128(N). K=256. va read ONCE; 1 block/CU.
__global__ __launch_bounds__(256) void gemm_out_kernel(
    const float* __restrict__ va,
    const unsigned short* __restrict__ B3t,
    const float* __restrict__ bias,
    float* __restrict__ out)
{
    const int t = threadIdx.x;
    const int wave = t >> 6, lane = t & 63;
    const int m = lane & 15, q = lane >> 4;
    const int W0 = blockIdx.x * 64 + wave * 16;

    f32x4 acc[8];
    #pragma unroll
    for (int cc = 0; cc < 8; ++cc) acc[cc] = (f32x4){0.f, 0.f, 0.f, 0.f};

    const float* arow = va + (size_t)(W0 + m) * 256;
    const unsigned short* brow = B3t + (size_t)m * 256;

    #pragma unroll 2
    for (int kc = 0; kc < 8; ++kc) {
        const int ko = kc * 32 + q * 8;
        const float4* ap = (const float4*)(arow + ko);
        float4 f0 = ap[0], f1 = ap[1];
        float xs[8] = {f0.x, f0.y, f0.z, f0.w, f1.x, f1.y, f1.z, f1.w};
        bf16x8 ah, al;
        #pragma unroll
        for (int jj = 0; jj < 8; ++jj) {
            unsigned short h = f2bf(xs[jj]);
            ah[jj] = (short)h;
            al[jj] = (short)f2bf(xs[jj] - bf2f(h));
        }
        bf16x8 bh[8], bl[8];
        #pragma unroll
        for (int ns = 0; ns < 8; ++ns) {
            const unsigned short* bp = brow + (size_t)ns * (16 * 256) + ko;
            bh[ns] = *(const bf16x8*)bp;
            bl[ns] = *(const bf16x8*)(bp + 128 * 256);
        }
        #pragma unroll
        for (int ns = 0; ns < 8; ++ns) acc[ns] = MFMA16(ah, bh[ns], acc[ns]);
        #pragma unroll
        for (int ns = 0; ns < 8; ++ns) acc[ns] = MFMA16(al, bh[ns], acc[ns]);
        #pragma unroll
        for (int ns = 0; ns < 8; ++ns) acc[ns] = MFMA16(ah, bl[ns], acc[ns]);
    }

    #pragma unroll
    for (int ns = 0; ns < 8; ++ns) {
        const int col = ns * 16 + m;
        #pragma unroll
        for (int r = 0; r < 4; ++r) {
            const int prow = W0 + q * 4 + r;                 // p' = j*128+i
            const int orow = ((prow & 127) << 7) | (prow >> 7);  // i*128+j
            out[(size_t)orow * 128 + col] = acc[ns][r] + bias[col];
        }
    }
}

// ---------------- MFMA fused triangle attention (bf16 E/G tables) -----------
// grid (j=128, h=8, br=2), 256 thr = 4 waves, wave owns 32-row strip.
// S-column c maps to K-row k(c) = (c&15)*8 + (c>>4); softmax is k-permutation
// invariant, and P/V use the same order, so the result is exact.
__global__ __launch_bounds__(256) void attn_kernel(
    const unsigned short* __restrict__ QT, const unsigned short* __restrict__ KT,
    const unsigned short* __restrict__ VT,
    const unsigned short* __restrict__ Etab, const unsigned short* __restrict__ Gtab,
    float* __restrict__ va)
{
    const int j = blockIdx.x, h = blockIdx.y, br = blockIdx.z;
    const int t = threadIdx.x;
    const int wave = t >> 6, lane = t & 63;
    const int m = lane & 15, q = lane >> 4;
    const int plane = br * 8 + h;
    const size_t SP = (size_t)NPOS * 8;          // ushorts per sub-plane
    const size_t jb = (size_t)j * 128 * 8;
    const unsigned short* __restrict__ Eb = Etab + (size_t)plane * NPOS;
    const unsigned short* __restrict__ Gb = Gtab + (size_t)plane * NPOS;

    __shared__ unsigned short Vth[16 * 136];
    __shared__ unsigned short Pl[128 * 136];

    const int strip = wave * 32;

    // ---- E preload into the MFMA accumulator (one u16x8 per (mt,r)) ----
    f32x4 S[2][8];
    #pragma unroll
    for (int mt = 0; mt < 2; ++mt)
        #pragma unroll
        for (int r = 0; r < 4; ++r) {
            const int i = strip + mt * 16 + q * 4 + r;
            u16x8 ev = *(const u16x8*)(Eb + (size_t)i * 128 + m * 8);
            #pragma unroll
            for (int nt = 0; nt < 8; ++nt) S[mt][nt][r] = bf2f(ev[nt]);
        }

    // stage V transposed+permuted into LDS: Vth[d*136 + c] = V[k(c)][d]
    {
        int c = t >> 1, ch = t & 1;
        int krow = (c & 15) * 8 + (c >> 4);
        const unsigned short* src = VT + (size_t)(plane * 2 + ch) * SP + jb
                                  + (size_t)krow * 8;
        u16x8 v = *(const u16x8*)src;
        #pragma unroll
        for (int dd = 0; dd < 8; ++dd)
            Vth[(ch * 8 + dd) * 136 + c] = v[dd];
    }

    const bf16x8 zero8 = {};
    const int hf = q & 1;
    const size_t qko = (size_t)(plane * 2 + hf) * SP + jb;

    // Q A-frags (direct from global; q>=2 lanes = zero K-half)
    bf16x8 aQ[2];
    #pragma unroll
    for (int mt = 0; mt < 2; ++mt) {
        const size_t off = qko + (size_t)(strip + mt * 16 + m) * 8;
        aQ[mt] = (q < 2) ? *(const bf16x8*)(QT + off) : zero8;
    }

    // S tiles: B row for tile nt, lane m = K row k = m*8 + nt (permuted)
    #pragma unroll
    for (int nt = 0; nt < 8; ++nt) {
        const size_t koff = qko + (size_t)(m * 8 + nt) * 8;
        bf16x8 bK = (q < 2) ? *(const bf16x8*)(KT + koff) : zero8;
        #pragma unroll
        for (int mt = 0; mt < 2; ++mt)
            S[mt][nt] = MFMA16(aQ[mt], bK, S[mt][nt]);
    }

    // softmax (row cols spread over lanes m: xor 1,2,4,8) + gate + P -> LDS
    #pragma unroll
    for (int mt = 0; mt < 2; ++mt)
        #pragma unroll
        for (int r = 0; r < 4; ++r) {
            float v = -1e30f;
            #pragma unroll
            for (int nt = 0; nt < 8; ++nt) v = fmaxf(v, S[mt][nt][r]);
            v = fmaxf(v, __shfl_xor(v, 1)); v = fmaxf(v, __shfl_xor(v, 2));
            v = fmaxf(v, __shfl_xor(v, 4)); v = fmaxf(v, __shfl_xor(v, 8));
            float s = 0.f;
            #pragma unroll
            for (int nt = 0; nt < 8; ++nt) {
                float p = __expf(S[mt][nt][r] - v);
                S[mt][nt][r] = p;
                s += p;
            }
            s += __shfl_xor(s, 1); s += __shfl_xor(s, 2);
            s += __shfl_xor(s, 4); s += __shfl_xor(s, 8);
            const float inv = 1.f / s;
            const int i = strip + mt * 16 + q * 4 + r;
            u16x8 gv = *(const u16x8*)(Gb + (size_t)i * 128 + m * 8);
            #pragma unroll
            for (int nt = 0; nt < 4; ++nt) {
                Pl[i * 136 + nt * 16 + m] =
                    f2bf(S[mt][nt][r] * inv * bf2f(gv[nt]));
                Pl[i * 136 + (nt + 4) * 16 + m] =
                    f2bf(S[mt][nt + 4][r] * inv * bf2f(gv[nt + 4]));
            }
        }

    __syncthreads();   // Vt ready (and P via lgkm drain)

    // AV = P @ V (both in permuted-k order)
    f32x4 av[2] = {(f32x4){0.f, 0.f, 0.f, 0.f}, (f32x4){0.f, 0.f, 0.f, 0.f}};
    #pragma unroll
    for (int kc = 0; kc < 4; ++kc) {
        const int off = kc * 32 + q * 8;
        bf16x8 bV = *(const bf16x8*)&Vth[m * 136 + off];
        #pragma unroll
        for (int mt = 0; mt < 2; ++mt) {
            bf16x8 aP = *(const bf16x8*)&Pl[(strip + mt * 16 + m) * 136 + off];
            av[mt] = MFMA16(aP, bV, av[mt]);
        }
    }

    // store va' (row p' = j*128+i, col k' = plane*16 + d): 64B-line coalesced
    #pragma unroll
    for (int mt = 0; mt < 2; ++mt)
        #pragma unroll
        for (int r = 0; r < 4; ++r) {
            const int i = strip + mt * 16 + q * 4 + r;
            va[((size_t)(j * 128 + i)) * 256 + plane * 16 + m] = av[mt][r];
        }
}

extern "C" void kernel_launch(void* const* d_in, const int* in_sizes, int n_in,
                              void* d_out, int out_size, void* d_ws, size_t ws_size,
                              hipStream_t stream) {
    const float* e        = (const float*)d_in[0];
    const float* mask     = (const float*)d_in[1];
    const float* ln_w     = (const float*)d_in[2];
    const float* ln_b     = (const float*)d_in[3];
    const float* w_qkv_in = (const float*)d_in[4];
    const float* b_qkv_in = (const float*)d_in[5];
    const float* w_eg_in  = (const float*)d_in[6];
    const float* b_eg_in  = (const float*)d_in[7];
    const float* w_qkv_o  = (const float*)d_in[8];
    const float* b_qkv_o  = (const float*)d_in[9];
    const float* w_eg_o   = (const float*)d_in[10];
    const float* b_eg_o   = (const float*)d_in[11];
    const float* w_o      = (const float*)d_in[12];
    const float* b_o      = (const float*)d_in[13];
    float* out = (float*)d_out;

    char* base = (char*)d_ws;
    const size_t PLANE = (size_t)16 * NPOS * 16;                      // ushorts per array
    unsigned short* e_hl = (unsigned short*)base;                     // 8.39 MB
    unsigned short* QT = (unsigned short*)(base + (size_t)NPOS * 256 * 2);
    unsigned short* KT = QT + PLANE;
    unsigned short* VT = KT + PLANE;
    float* va = (float*)(VT + PLANE);                                 // 16.78 MB
    unsigned short* Etab = (unsigned short*)(va + (size_t)NPOS * 256);// 0.52 MB (bf16)
    unsigned short* Gtab = Etab + (size_t)16 * NPOS;                  // 0.52 MB
    unsigned short* B3t  = Gtab + (size_t)16 * NPOS;                  // 0.13 MB

    // aliases (lifetime-checked): B1t/B2t overlay va (dead before attn writes)
    unsigned short* B1t = (unsigned short*)va;
    unsigned short* B2t = B1t + (size_t)2 * 448 * 128;

    prep_kernel<<<4672, 256, 0, stream>>>(
        e, ln_w, ln_b, e_hl,
        w_qkv_in, w_eg_in, B1t, w_qkv_o, w_eg_o, B2t, w_o, B3t);

    gemm_qkv_kernel<<<dim3(128, 7, 2), 256, 0, stream>>>(
        e_hl, B1t, B2t, b_qkv_in, b_eg_in, b_qkv_o, b_eg_o, mask,
        QT, KT, VT, Etab, Gtab);

    attn_kernel<<<dim3(128, 8, 2), 256, 0, stream>>>(
        QT, KT, VT, Etab, Gtab, va);

    gemm_out_kernel<<<256, 256, 0, stream>>>(va, B3t, b_o, out);
}